// Round 1
// baseline (372.338 us; speedup 1.0000x reference)
//
#include <hip/hip_runtime.h>
#include <hip/hip_bf16.h>

typedef __bf16 bf16;
typedef __bf16 bf16x4 __attribute__((ext_vector_type(4)));
typedef __bf16 bf16x8 __attribute__((ext_vector_type(8)));
typedef float  f32x4  __attribute__((ext_vector_type(4)));

#define H_DIM 1024
#define S_DIM 1024
#define K_DIM 256
#define BK_ROWS 4096          // B*K rows per span type
#define KT 32                 // K-tile per LDS stage (one MFMA k-step)
#define ASTR 40               // KT + 8 pad: breaks bank stride, keeps 16B align (80B rows)
#define PLANE (1024*1024)     // one weight plane, elements

__device__ __forceinline__ void bf_split(float f, bf16& hi, bf16& lo) {
    hi = (bf16)f;                 // RNE
    lo = (bf16)(f - (float)hi);   // exact subtraction (Sterbenz), then RNE
}

// Fold weights: Wa = W1+W3, Wb = W2-W3, W4; split each into bf16 hi/lo planes.
// ws layout per span: [Wa_hi, Wa_lo, Wb_hi, Wb_lo, W4_hi, W4_lo], each (H,H) row-major (o, h).
__global__ __launch_bounds__(256) void prep_weights(
    const float* __restrict__ Wp1, const float* __restrict__ Wp2,
    const float* __restrict__ Wp3, const float* __restrict__ Wp4,
    const float* __restrict__ Wh1, const float* __restrict__ Wh2,
    const float* __restrict__ Wh3, const float* __restrict__ Wh4,
    bf16* __restrict__ ws)
{
    const int span = blockIdx.y;
    const float* W1 = span ? Wh1 : Wp1;
    const float* W2 = span ? Wh2 : Wp2;
    const float* W3 = span ? Wh3 : Wp3;
    const float* W4 = span ? Wh4 : Wp4;
    bf16* base = ws + (size_t)span * 6 * PLANE;

    size_t i = ((size_t)blockIdx.x * 256 + threadIdx.x) * 4;
    f32x4 w1 = *(const f32x4*)(W1 + i);
    f32x4 w2 = *(const f32x4*)(W2 + i);
    f32x4 w3 = *(const f32x4*)(W3 + i);
    f32x4 w4 = *(const f32x4*)(W4 + i);

    bf16x4 wah, wal, wbh, wbl, w4h, w4l;
#pragma unroll
    for (int j = 0; j < 4; ++j) {
        bf16 h, l;
        bf_split(w1[j] + w3[j], h, l); wah[j] = h; wal[j] = l;
        bf_split(w2[j] - w3[j], h, l); wbh[j] = h; wbl[j] = l;
        bf_split(w4[j],         h, l); w4h[j] = h; w4l[j] = l;
    }
    *(bf16x4*)(base + 0*PLANE + i) = wah;
    *(bf16x4*)(base + 1*PLANE + i) = wal;
    *(bf16x4*)(base + 2*PLANE + i) = wbh;
    *(bf16x4*)(base + 3*PLANE + i) = wbl;
    *(bf16x4*)(base + 4*PLANE + i) = w4h;
    *(bf16x4*)(base + 5*PLANE + i) = w4l;
}

// Fused gather + 4-product split-bf16 GEMM + bias/product/tanh epilogue.
// Grid: (64 m-tiles, 16 n-tiles, 2 spans). Block: 256 (4 waves, 2x2 of 32x32).
__global__ __launch_bounds__(256) void span_gemm(
    const float* __restrict__ x,
    const int* __restrict__ idxP, const int* __restrict__ idxH,
    const bf16* __restrict__ ws,
    const float* __restrict__ bp1, const float* __restrict__ bp2, const float* __restrict__ bp4,
    const float* __restrict__ bh1, const float* __restrict__ bh2, const float* __restrict__ bh4,
    float* __restrict__ out)
{
    const int t     = threadIdx.x;
    const int mtile = blockIdx.x;   // 64 tiles of 64 bk-rows
    const int ntile = blockIdx.y;   // 16 tiles of 64 o-cols
    const int span  = blockIdx.z;

    const int*  idx   = span ? idxH : idxP;
    const bf16* wbase = ws + (size_t)span * 6 * PLANE;
    const float* b1 = span ? bh1 : bp1;
    const float* b2 = span ? bh2 : bp2;
    const float* b4 = span ? bh4 : bp4;
    float* obase = out + (size_t)span * BK_ROWS * H_DIM;

    // A planes: 0 = xs_hi, 1 = xs_lo, 2 = xe_hi, 3 = xe_lo
    __shared__ __align__(16) bf16 A_lds[4][64 * ASTR];
    // B planes match ws order: Wa_hi, Wa_lo, Wb_hi, Wb_lo, W4_hi, W4_lo
    __shared__ __align__(16) bf16 B_lds[6][64 * ASTR];
    __shared__ int rowoff[2][64];   // float-offset of gathered x row, per side

    if (t < 128) {
        int side = t >> 6;          // 0 = start, 1 = end
        int m = t & 63;
        int bk = mtile * 64 + m;
        int b  = bk >> 8;           // / K_DIM
        int kk = bk & 255;
        int id = idx[b * (2 * K_DIM) + side * K_DIM + kk];
        rowoff[side][m] = (b * S_DIM + id) * H_DIM;
    }
    __syncthreads();

    f32x4 accL[2][2], acc4s[2][2], acc4e[2][2];
    {
        f32x4 z = {0.f, 0.f, 0.f, 0.f};
#pragma unroll
        for (int mf = 0; mf < 2; ++mf)
#pragma unroll
            for (int nf = 0; nf < 2; ++nf) {
                accL[mf][nf] = z; acc4s[mf][nf] = z; acc4e[mf][nf] = z;
            }
    }

    const int wid  = t >> 6;
    const int lane = t & 63;
    const int wm   = (wid & 1) * 32;
    const int wn   = (wid >> 1) * 32;
    const int lrow = lane & 15;
    const int lq   = lane >> 4;

    const int am  = t >> 3;         // 0..31 (A stage row, x2 halves)
    const int ak  = (t & 7) * 4;    // 0..28 (A stage col, float4)
    const int bn  = t >> 2;         // 0..63 (B stage row)
    const int bk8 = (t & 3) * 8;    // B stage col, bf16x8
    const size_t brow = (size_t)(ntile * 64 + bn) * H_DIM + bk8;

    for (int k0 = 0; k0 < H_DIM; k0 += KT) {
        // ---- stage A: gather fp32 rows, split to bf16 hi/lo in-flight ----
#pragma unroll
        for (int h2 = 0; h2 < 2; ++h2) {
            int m = h2 * 32 + am;
#pragma unroll
            for (int side = 0; side < 2; ++side) {
                const float* pr = x + rowoff[side][m] + k0 + ak;
                f32x4 v = *(const f32x4*)pr;
                bf16x4 vh, vl;
#pragma unroll
                for (int j = 0; j < 4; ++j) { bf16 h, l; bf_split(v[j], h, l); vh[j] = h; vl[j] = l; }
                *(bf16x4*)&A_lds[side * 2 + 0][m * ASTR + ak] = vh;
                *(bf16x4*)&A_lds[side * 2 + 1][m * ASTR + ak] = vl;
            }
        }
        // ---- stage B: pre-split weight planes, 16B vector loads ----
#pragma unroll
        for (int p = 0; p < 6; ++p) {
            bf16x8 v = *(const bf16x8*)(wbase + (size_t)p * PLANE + brow + k0);
            *(bf16x8*)&B_lds[p][bn * ASTR + bk8] = v;
        }
        __syncthreads();

        // ---- fragments (A: m=lane&15, k=quad*8+j ; B: n=lane&15, k=quad*8+j) ----
        bf16x8 afr[4][2], bfr[6][2];
#pragma unroll
        for (int mf = 0; mf < 2; ++mf) {
            int r = (wm + mf * 16 + lrow) * ASTR + lq * 8;
#pragma unroll
            for (int ty = 0; ty < 4; ++ty)
                afr[ty][mf] = *(const bf16x8*)&A_lds[ty][r];
        }
#pragma unroll
        for (int nf = 0; nf < 2; ++nf) {
            int r = (wn + nf * 16 + lrow) * ASTR + lq * 8;
#pragma unroll
            for (int p = 0; p < 6; ++p)
                bfr[p][nf] = *(const bf16x8*)&B_lds[p][r];
        }

        // ---- 12 MFMAs per fragment pair: hi*hi + hi*lo + lo*hi for each product ----
#pragma unroll
        for (int mf = 0; mf < 2; ++mf)
#pragma unroll
            for (int nf = 0; nf < 2; ++nf) {
                f32x4 L = accL[mf][nf];
                L = __builtin_amdgcn_mfma_f32_16x16x32_bf16(afr[0][mf], bfr[0][nf], L, 0, 0, 0); // xs_hi*Wa_hi
                L = __builtin_amdgcn_mfma_f32_16x16x32_bf16(afr[0][mf], bfr[1][nf], L, 0, 0, 0); // xs_hi*Wa_lo
                L = __builtin_amdgcn_mfma_f32_16x16x32_bf16(afr[1][mf], bfr[0][nf], L, 0, 0, 0); // xs_lo*Wa_hi
                L = __builtin_amdgcn_mfma_f32_16x16x32_bf16(afr[2][mf], bfr[2][nf], L, 0, 0, 0); // xe_hi*Wb_hi
                L = __builtin_amdgcn_mfma_f32_16x16x32_bf16(afr[2][mf], bfr[3][nf], L, 0, 0, 0); // xe_hi*Wb_lo
                L = __builtin_amdgcn_mfma_f32_16x16x32_bf16(afr[3][mf], bfr[2][nf], L, 0, 0, 0); // xe_lo*Wb_hi
                accL[mf][nf] = L;
                f32x4 P = acc4s[mf][nf];
                P = __builtin_amdgcn_mfma_f32_16x16x32_bf16(afr[0][mf], bfr[4][nf], P, 0, 0, 0);
                P = __builtin_amdgcn_mfma_f32_16x16x32_bf16(afr[0][mf], bfr[5][nf], P, 0, 0, 0);
                P = __builtin_amdgcn_mfma_f32_16x16x32_bf16(afr[1][mf], bfr[4][nf], P, 0, 0, 0);
                acc4s[mf][nf] = P;
                f32x4 Q = acc4e[mf][nf];
                Q = __builtin_amdgcn_mfma_f32_16x16x32_bf16(afr[2][mf], bfr[4][nf], Q, 0, 0, 0);
                Q = __builtin_amdgcn_mfma_f32_16x16x32_bf16(afr[2][mf], bfr[5][nf], Q, 0, 0, 0);
                Q = __builtin_amdgcn_mfma_f32_16x16x32_bf16(afr[3][mf], bfr[4][nf], Q, 0, 0, 0);
                acc4e[mf][nf] = Q;
            }
        __syncthreads();
    }

    // ---- epilogue: span = L + b1 + b2 + (P4s+b4)*(P4e+b4); out = tanh(span) ----
    // C/D layout (m89-verified): col = lane&15, row = (lane>>4)*4 + i
#pragma unroll
    for (int mf = 0; mf < 2; ++mf)
#pragma unroll
        for (int nf = 0; nf < 2; ++nf) {
            int col = ntile * 64 + wn + nf * 16 + lrow;
            float bb12 = b1[col] + b2[col];
            float bb4  = b4[col];
            int row0 = mtile * 64 + wm + mf * 16 + lq * 4;
#pragma unroll
            for (int i = 0; i < 4; ++i) {
                float v = accL[mf][nf][i] + bb12
                        + (acc4s[mf][nf][i] + bb4) * (acc4e[mf][nf][i] + bb4);
                obase[(size_t)(row0 + i) * H_DIM + col] = tanhf(v);
            }
        }
}

extern "C" void kernel_launch(void* const* d_in, const int* in_sizes, int n_in,
                              void* d_out, int out_size, void* d_ws, size_t ws_size,
                              hipStream_t stream) {
    (void)in_sizes; (void)n_in; (void)out_size; (void)ws_size;
    const float* x    = (const float*)d_in[0];
    const int*   idxP = (const int*)d_in[1];
    const int*   idxH = (const int*)d_in[2];
    const float* Wp1 = (const float*)d_in[3];  const float* bp1 = (const float*)d_in[4];
    const float* Wp2 = (const float*)d_in[5];  const float* bp2 = (const float*)d_in[6];
    const float* Wp3 = (const float*)d_in[7];
    const float* Wp4 = (const float*)d_in[9];  const float* bp4 = (const float*)d_in[10];
    const float* Wh1 = (const float*)d_in[11]; const float* bh1 = (const float*)d_in[12];
    const float* Wh2 = (const float*)d_in[13]; const float* bh2 = (const float*)d_in[14];
    const float* Wh3 = (const float*)d_in[15];
    const float* Wh4 = (const float*)d_in[17]; const float* bh4 = (const float*)d_in[18];
    float* out = (float*)d_out;
    bf16*  ws  = (bf16*)d_ws;   // 2 spans * 6 planes * 2MB = 24 MB

    prep_weights<<<dim3(1024, 2), 256, 0, stream>>>(Wp1, Wp2, Wp3, Wp4,
                                                    Wh1, Wh2, Wh3, Wh4, ws);
    span_gemm<<<dim3(64, 16, 2), 256, 0, stream>>>(x, idxP, idxH, ws,
                                                   bp1, bp2, bp4, bh1, bh2, bh4, out);
}

// Round 2
// 344.412 us; speedup vs baseline: 1.0811x; 1.0811x over previous
//
#include <hip/hip_runtime.h>
#include <hip/hip_bf16.h>

typedef _Float16 f16;
typedef _Float16 f16x4 __attribute__((ext_vector_type(4)));
typedef _Float16 f16x8 __attribute__((ext_vector_type(8)));
typedef float    f32x4 __attribute__((ext_vector_type(4)));

#define H_DIM 1024
#define S_DIM 1024
#define PLANE (1024*1024)
#define KT 32
#define ASTR 40          // A row stride in f16: 32 + 8 pad (80 B = 5x16B, conflict-uniform)

// global -> LDS direct DMA, 16 B per lane; LDS dest = wave-uniform base + lane*16
__device__ __forceinline__ void load_lds16(const void* g, void* l) {
    __builtin_amdgcn_global_load_lds(
        (const __attribute__((address_space(1))) void*)g,
        (__attribute__((address_space(3))) void*)l, 16, 0, 0);
}

// Fold weights: Wa = W1+W3, Wb = W2-W3, W4 -> fp16 planes.
// ws layout per span: [Wa, Wb, W4], each (H,H) row-major (o,h).
__global__ __launch_bounds__(256) void prep_weights(
    const float* __restrict__ Wp1, const float* __restrict__ Wp2,
    const float* __restrict__ Wp3, const float* __restrict__ Wp4,
    const float* __restrict__ Wh1, const float* __restrict__ Wh2,
    const float* __restrict__ Wh3, const float* __restrict__ Wh4,
    f16* __restrict__ ws)
{
    const int span = blockIdx.y;
    const float* W1 = span ? Wh1 : Wp1;
    const float* W2 = span ? Wh2 : Wp2;
    const float* W3 = span ? Wh3 : Wp3;
    const float* W4 = span ? Wh4 : Wp4;
    f16* base = ws + (size_t)span * 3 * PLANE;

    size_t i = ((size_t)blockIdx.x * 256 + threadIdx.x) * 4;
    f32x4 w1 = *(const f32x4*)(W1 + i);
    f32x4 w2 = *(const f32x4*)(W2 + i);
    f32x4 w3 = *(const f32x4*)(W3 + i);
    f32x4 w4 = *(const f32x4*)(W4 + i);

    f16x4 wa, wb, wc;
#pragma unroll
    for (int j = 0; j < 4; ++j) {
        wa[j] = (f16)(w1[j] + w3[j]);
        wb[j] = (f16)(w2[j] - w3[j]);
        wc[j] = (f16)w4[j];
    }
    *(f16x4*)(base + 0*PLANE + i) = wa;
    *(f16x4*)(base + 1*PLANE + i) = wb;
    *(f16x4*)(base + 2*PLANE + i) = wc;
}

// Fused gather + 4-plane fp16 GEMM + bias/product/tanh epilogue.
// Grid: (64 m-tiles, 16 n-tiles, 2 spans). Block: 256 (4 waves, 2x2 of 32x32).
__global__ __launch_bounds__(256) void span_gemm(
    const float* __restrict__ x,
    const int* __restrict__ idxP, const int* __restrict__ idxH,
    const f16* __restrict__ wpl,
    const float* __restrict__ bp1, const float* __restrict__ bp2, const float* __restrict__ bp4,
    const float* __restrict__ bh1, const float* __restrict__ bh2, const float* __restrict__ bh4,
    float* __restrict__ out)
{
    const int t     = threadIdx.x;
    const int mtile = blockIdx.x;   // 64 tiles of 64 bk-rows
    const int ntile = blockIdx.y;   // 16 tiles of 64 o-cols
    const int span  = blockIdx.z;

    const int* idx    = span ? idxH : idxP;
    const f16* wbase  = wpl + (size_t)span * 3 * PLANE;
    const float* b1 = span ? bh1 : bp1;
    const float* b2 = span ? bh2 : bp2;
    const float* b4 = span ? bh4 : bp4;
    float* obase = out + (size_t)span * 4096 * H_DIM;

    // A planes: 0 = xs, 1 = xe (padded rows, VALU-staged with f32->f16 cvt)
    __shared__ __align__(16) f16 A_lds[2][64 * ASTR];
    // B planes: Wa, Wb, W4 — packed 64x32 rows (64 B), filled by global_load_lds
    __shared__ __align__(16) f16 B_lds[3 * 64 * 32];
    __shared__ int rowoff[2][64];   // float-offset of gathered x row, per side

    if (t < 128) {
        int side = t >> 6;
        int m = t & 63;
        int bk = mtile * 64 + m;
        int b  = bk >> 8;
        int kk = bk & 255;
        int id = idx[b * 512 + side * 256 + kk];
        rowoff[side][m] = (b * S_DIM + id) * H_DIM;
    }
    __syncthreads();

    const int wid  = t >> 6;
    const int lane = t & 63;
    const int wm   = (wid & 1) * 32;
    const int wn   = (wid >> 1) * 32;
    const int lrow = lane & 15;
    const int lq   = lane >> 4;

    // ---- A staging coords: thread covers (row = t&63, k-seg = (t>>6)*8) ----
    const int ar = t & 63;
    const int aq = (t >> 6) * 8;
    const float* ap0 = x + rowoff[0][ar] + aq;
    const float* ap1 = x + rowoff[1][ar] + aq;
    f16* adst0 = &A_lds[0][ar * ASTR + aq];
    f16* adst1 = &A_lds[1][ar * ASTR + aq];

    // ---- B staging: 12 global_load_lds tasks per kstep, 3 per wave ----
    // task tk = p*4+g: plane p rows [g*16, g*16+16), lane -> (row=lane>>2, seg=lane&3)
    const f16* bptr[3];
    unsigned bofs[3];
#pragma unroll
    for (int j = 0; j < 3; ++j) {
        int tk = wid * 3 + j;
        int p = tk >> 2, g = tk & 3;
        int grow = ntile * 64 + g * 16 + (lane >> 2);
        bptr[j] = wbase + (size_t)p * PLANE + (size_t)grow * H_DIM + (lane & 3) * 8;
        bofs[j] = p * 4096 + g * 1024;   // bytes
    }

    f32x4 accL[2][2], accP[2][2], accQ[2][2];
    {
        f32x4 z = {0.f, 0.f, 0.f, 0.f};
#pragma unroll
        for (int mf = 0; mf < 2; ++mf)
#pragma unroll
            for (int nf = 0; nf < 2; ++nf) { accL[mf][nf] = z; accP[mf][nf] = z; accQ[mf][nf] = z; }
    }

    for (int k0 = 0; k0 < H_DIM; k0 += KT) {
        // ---- stage A: gather fp32, cvt fp16, one b128 write per side ----
        {
            f32x4 u0 = *(const f32x4*)(ap0 + k0);
            f32x4 u1 = *(const f32x4*)(ap0 + k0 + 4);
            f32x4 v0 = *(const f32x4*)(ap1 + k0);
            f32x4 v1 = *(const f32x4*)(ap1 + k0 + 4);
            f16x8 hu, hv;
#pragma unroll
            for (int j = 0; j < 4; ++j) {
                hu[j] = (f16)u0[j]; hu[4 + j] = (f16)u1[j];
                hv[j] = (f16)v0[j]; hv[4 + j] = (f16)v1[j];
            }
            *(f16x8*)adst0 = hu;
            *(f16x8*)adst1 = hv;
        }
        // ---- stage B: direct global->LDS DMA (no VGPR round-trip) ----
#pragma unroll
        for (int j = 0; j < 3; ++j)
            load_lds16(bptr[j] + k0, (char*)B_lds + bofs[j]);

        __syncthreads();   // drains vmcnt (global_load_lds) + lgkmcnt, publishes LDS

        // ---- fragments: A m=lane&15, k=quad*8+j ; B n=lane&15, k=quad*8+j ----
        f16x8 afr[2][2], bfr[3][2];
#pragma unroll
        for (int mf = 0; mf < 2; ++mf) {
            int r = (wm + mf * 16 + lrow) * ASTR + lq * 8;
            afr[0][mf] = *(const f16x8*)&A_lds[0][r];
            afr[1][mf] = *(const f16x8*)&A_lds[1][r];
        }
#pragma unroll
        for (int nf = 0; nf < 2; ++nf) {
            int rb = (wn + nf * 16 + lrow) * 32 + lq * 8;
#pragma unroll
            for (int p = 0; p < 3; ++p)
                bfr[p][nf] = *(const f16x8*)&B_lds[p * 2048 + rb];
        }

        // ---- 4 MFMAs per fragment pair: L += xs*Wa + xe*Wb; P += xs*W4; Q += xe*W4 ----
#pragma unroll
        for (int mf = 0; mf < 2; ++mf)
#pragma unroll
            for (int nf = 0; nf < 2; ++nf) {
                accL[mf][nf] = __builtin_amdgcn_mfma_f32_16x16x32_f16(afr[0][mf], bfr[0][nf], accL[mf][nf], 0, 0, 0);
                accL[mf][nf] = __builtin_amdgcn_mfma_f32_16x16x32_f16(afr[1][mf], bfr[1][nf], accL[mf][nf], 0, 0, 0);
                accP[mf][nf] = __builtin_amdgcn_mfma_f32_16x16x32_f16(afr[0][mf], bfr[2][nf], accP[mf][nf], 0, 0, 0);
                accQ[mf][nf] = __builtin_amdgcn_mfma_f32_16x16x32_f16(afr[1][mf], bfr[2][nf], accQ[mf][nf], 0, 0, 0);
            }
        __syncthreads();   // all waves done reading before next stage overwrites
    }

    // ---- epilogue: span = L + b1 + b2 + (P+b4)*(Q+b4); out = tanh(span) ----
    // C/D layout (m89-verified): col = lane&15, row = (lane>>4)*4 + i
#pragma unroll
    for (int mf = 0; mf < 2; ++mf)
#pragma unroll
        for (int nf = 0; nf < 2; ++nf) {
            int col = ntile * 64 + wn + nf * 16 + lrow;
            float bb12 = b1[col] + b2[col];
            float bb4  = b4[col];
            int row0 = mtile * 64 + wm + mf * 16 + lq * 4;
#pragma unroll
            for (int i = 0; i < 4; ++i) {
                float v = accL[mf][nf][i] + bb12
                        + (accP[mf][nf][i] + bb4) * (accQ[mf][nf][i] + bb4);
                obase[(size_t)(row0 + i) * H_DIM + col] = tanhf(v);
            }
        }
}

extern "C" void kernel_launch(void* const* d_in, const int* in_sizes, int n_in,
                              void* d_out, int out_size, void* d_ws, size_t ws_size,
                              hipStream_t stream) {
    (void)in_sizes; (void)n_in; (void)out_size; (void)ws_size;
    const float* x    = (const float*)d_in[0];
    const int*   idxP = (const int*)d_in[1];
    const int*   idxH = (const int*)d_in[2];
    const float* Wp1 = (const float*)d_in[3];  const float* bp1 = (const float*)d_in[4];
    const float* Wp2 = (const float*)d_in[5];  const float* bp2 = (const float*)d_in[6];
    const float* Wp3 = (const float*)d_in[7];
    const float* Wp4 = (const float*)d_in[9];  const float* bp4 = (const float*)d_in[10];
    const float* Wh1 = (const float*)d_in[11]; const float* bh1 = (const float*)d_in[12];
    const float* Wh2 = (const float*)d_in[13]; const float* bh2 = (const float*)d_in[14];
    const float* Wh3 = (const float*)d_in[15];
    const float* Wh4 = (const float*)d_in[17]; const float* bh4 = (const float*)d_in[18];
    float* out = (float*)d_out;
    f16*   ws  = (f16*)d_ws;   // 2 spans * 3 planes * 2MB = 12 MB

    prep_weights<<<dim3(1024, 2), 256, 0, stream>>>(Wp1, Wp2, Wp3, Wp4,
                                                    Wh1, Wh2, Wh3, Wh4, ws);
    span_gemm<<<dim3(64, 16, 2), 256, 0, stream>>>(x, idxP, idxH, ws,
                                                   bp1, bp2, bp4, bh1, bh2, bh4, out);
}

// Round 3
// 255.892 us; speedup vs baseline: 1.4551x; 1.3459x over previous
//
#include <hip/hip_runtime.h>
#include <hip/hip_bf16.h>

typedef _Float16 f16;
typedef _Float16 f16x4 __attribute__((ext_vector_type(4)));
typedef _Float16 f16x8 __attribute__((ext_vector_type(8)));
typedef float    f32x4 __attribute__((ext_vector_type(4)));

#define H_DIM 1024
#define S_DIM 1024
#define PLANE (1024*1024)
#define MT 128
#define NT 64
#define KT 32
#define XOFF (6*PLANE)   // x_f16 starts after 2 spans * 3 weight planes (f16 elems)

// global -> LDS direct DMA, 16 B per lane; LDS dest = wave-uniform base + lane*16
__device__ __forceinline__ void load_lds16(const f16* g, f16* l) {
    __builtin_amdgcn_global_load_lds(
        (const __attribute__((address_space(1))) void*)g,
        (__attribute__((address_space(3))) void*)l, 16, 0, 0);
}

// Fold weights: Wa = W1+W3, Wb = W2-W3, W4 -> fp16 planes.
// ws layout per span: [Wa, Wb, W4], each (H,H) row-major (o,h).
__global__ __launch_bounds__(256) void prep_weights(
    const float* __restrict__ Wp1, const float* __restrict__ Wp2,
    const float* __restrict__ Wp3, const float* __restrict__ Wp4,
    const float* __restrict__ Wh1, const float* __restrict__ Wh2,
    const float* __restrict__ Wh3, const float* __restrict__ Wh4,
    f16* __restrict__ ws)
{
    const int span = blockIdx.y;
    const float* W1 = span ? Wh1 : Wp1;
    const float* W2 = span ? Wh2 : Wp2;
    const float* W3 = span ? Wh3 : Wp3;
    const float* W4 = span ? Wh4 : Wp4;
    f16* base = ws + (size_t)span * 3 * PLANE;

    size_t i = ((size_t)blockIdx.x * 256 + threadIdx.x) * 4;
    f32x4 w1 = *(const f32x4*)(W1 + i);
    f32x4 w2 = *(const f32x4*)(W2 + i);
    f32x4 w3 = *(const f32x4*)(W3 + i);
    f32x4 w4 = *(const f32x4*)(W4 + i);

    f16x4 wa, wb, wc;
#pragma unroll
    for (int j = 0; j < 4; ++j) {
        wa[j] = (f16)(w1[j] + w3[j]);
        wb[j] = (f16)(w2[j] - w3[j]);
        wc[j] = (f16)w4[j];
    }
    *(f16x4*)(base + 0*PLANE + i) = wa;
    *(f16x4*)(base + 1*PLANE + i) = wb;
    *(f16x4*)(base + 2*PLANE + i) = wc;
}

// x (B,S,H) fp32 -> fp16 copy in ws (enables global_load_lds DMA for A staging)
__global__ __launch_bounds__(256) void prep_x(const float* __restrict__ x,
                                              f16* __restrict__ xh)
{
    size_t i = ((size_t)blockIdx.x * 256 + threadIdx.x) * 4;
    f32x4 v = *(const f32x4*)(x + i);
    f16x4 h;
#pragma unroll
    for (int j = 0; j < 4; ++j) h[j] = (f16)v[j];
    *(f16x4*)(xh + i) = h;
}

// Fused gather + 4-plane fp16 GEMM + bias/product/tanh epilogue.
// 128x64 tile, KT=32, single-barrier double-buffered DMA pipeline.
// Grid: (32 m-tiles, 16 n-tiles, 2 spans). Block: 256 (4 waves, 2x2 of 64x32).
__global__ __launch_bounds__(256) void span_gemm(
    const f16* __restrict__ xh,
    const int* __restrict__ idxP, const int* __restrict__ idxH,
    const f16* __restrict__ wpl,
    const float* __restrict__ bp1, const float* __restrict__ bp2, const float* __restrict__ bp4,
    const float* __restrict__ bh1, const float* __restrict__ bh2, const float* __restrict__ bh4,
    float* __restrict__ out)
{
    const int t     = threadIdx.x;
    const int mtile = blockIdx.x;   // 32 tiles of 128 bk-rows
    const int ntile = blockIdx.y;   // 16 tiles of 64 o-cols
    const int span  = blockIdx.z;

    const int* idx   = span ? idxH : idxP;
    const f16* wbase = wpl + (size_t)span * 3 * PLANE;
    const float* b1 = span ? bh1 : bp1;
    const float* b2 = span ? bh2 : bp2;
    const float* b4 = span ? bh4 : bp4;
    float* obase = out + (size_t)span * 4096 * H_DIM;

    // A: [buf][plane(2) * 128rows * 32k]  — unpadded (DMA layout), 16 KB/buf
    __shared__ __align__(16) f16 A_lds[2][2 * MT * KT];
    // B: [buf][plane(3) * 64rows * 32k]   — unpadded, 12 KB/buf
    __shared__ __align__(16) f16 B_lds[2][3 * NT * KT];
    __shared__ int rowoff[2][MT];   // f16-offset of gathered x row, per side

    {   // all 256 threads: 2 sides x 128 rows
        int side = t >> 7;
        int m = t & 127;
        int bk = mtile * MT + m;
        int b  = bk >> 8;
        int kk = bk & 255;
        int id = idx[b * 512 + side * 256 + kk];
        rowoff[side][m] = (b * S_DIM + id) * H_DIM;
    }
    __syncthreads();

    const int wid  = t >> 6;
    const int lane = t & 63;

    // ---- DMA task tables (per wave: 4 A ops + 3 B ops per k-step) ----
    // Each op moves 16 rows x 64 B (one contiguous 1 KB LDS block).
    // lane -> row = lane>>2, 16B-seg = lane&3 (matches HW lane*16 dest rule).
    const f16* asrc[4]; int adst[4];
#pragma unroll
    for (int j = 0; j < 4; ++j) {
        int o = wid * 4 + j;          // 0..15
        int p = o >> 3, g = o & 7;    // plane (side), row-group of 16
        int r = g * 16 + (lane >> 2);
        asrc[j] = xh + rowoff[p][r] + (lane & 3) * 8;
        adst[j] = p * (MT * KT) + g * 16 * KT;      // wave-uniform
    }
    const f16* bsrc[3]; int bdst[3];
#pragma unroll
    for (int j = 0; j < 3; ++j) {
        int o = wid * 3 + j;          // 0..11
        int p = o >> 2, g = o & 3;
        int grow = ntile * NT + g * 16 + (lane >> 2);
        bsrc[j] = wbase + (size_t)p * PLANE + (size_t)grow * H_DIM + (lane & 3) * 8;
        bdst[j] = p * (NT * KT) + g * 16 * KT;      // wave-uniform
    }

    f32x4 accL[4][2], accP[4][2], accQ[4][2];
    {
        f32x4 z = {0.f, 0.f, 0.f, 0.f};
#pragma unroll
        for (int mf = 0; mf < 4; ++mf)
#pragma unroll
            for (int nf = 0; nf < 2; ++nf) { accL[mf][nf] = z; accP[mf][nf] = z; accQ[mf][nf] = z; }
    }

    const int wm   = (wid & 1) * 64;   // wave covers rows [wm, wm+64)
    const int wn   = (wid >> 1) * 32;  // cols [wn, wn+32)
    const int lrow = lane & 15;
    const int lq   = lane >> 4;

    // ---- prologue: DMA k-step 0 into buf 0 ----
#pragma unroll
    for (int j = 0; j < 4; ++j) load_lds16(asrc[j], &A_lds[0][adst[j]]);
#pragma unroll
    for (int j = 0; j < 3; ++j) load_lds16(bsrc[j], &B_lds[0][bdst[j]]);
    __syncthreads();

    for (int ks = 0; ks < H_DIM / KT; ++ks) {
        const int cur = ks & 1;
        // ---- prefetch k-step ks+1 into the other buffer (overlaps compute) ----
        if (ks < H_DIM / KT - 1) {
            const int k0 = (ks + 1) * KT;
            const int nb = cur ^ 1;
#pragma unroll
            for (int j = 0; j < 4; ++j) load_lds16(asrc[j] + k0, &A_lds[nb][adst[j]]);
#pragma unroll
            for (int j = 0; j < 3; ++j) load_lds16(bsrc[j] + k0, &B_lds[nb][bdst[j]]);
        }

        // ---- fragments: A m=lane&15, k=quad*8+j ; B n=lane&15, k=quad*8+j ----
        f16x8 afr[2][4], bfr[3][2];
#pragma unroll
        for (int mf = 0; mf < 4; ++mf) {
            int r = (wm + mf * 16 + lrow) * KT + lq * 8;
            afr[0][mf] = *(const f16x8*)&A_lds[cur][r];
            afr[1][mf] = *(const f16x8*)&A_lds[cur][MT * KT + r];
        }
#pragma unroll
        for (int nf = 0; nf < 2; ++nf) {
            int r = (wn + nf * 16 + lrow) * KT + lq * 8;
#pragma unroll
            for (int p = 0; p < 3; ++p)
                bfr[p][nf] = *(const f16x8*)&B_lds[cur][p * (NT * KT) + r];
        }

        // ---- 4 MFMAs per (mf,nf): L += xs*Wa + xe*Wb; P += xs*W4; Q += xe*W4 ----
#pragma unroll
        for (int mf = 0; mf < 4; ++mf)
#pragma unroll
            for (int nf = 0; nf < 2; ++nf) {
                accL[mf][nf] = __builtin_amdgcn_mfma_f32_16x16x32_f16(afr[0][mf], bfr[0][nf], accL[mf][nf], 0, 0, 0);
                accL[mf][nf] = __builtin_amdgcn_mfma_f32_16x16x32_f16(afr[1][mf], bfr[1][nf], accL[mf][nf], 0, 0, 0);
                accP[mf][nf] = __builtin_amdgcn_mfma_f32_16x16x32_f16(afr[0][mf], bfr[2][nf], accP[mf][nf], 0, 0, 0);
                accQ[mf][nf] = __builtin_amdgcn_mfma_f32_16x16x32_f16(afr[1][mf], bfr[2][nf], accQ[mf][nf], 0, 0, 0);
            }

        // one barrier: confirms prefetch landed (vmcnt drain) + cur buf reusable
        __syncthreads();
    }

    // ---- epilogue: span = L + b1 + b2 + (P+b4)*(Q+b4); out = tanh(span) ----
    // C/D layout (m89-verified): col = lane&15, row = (lane>>4)*4 + i
#pragma unroll
    for (int mf = 0; mf < 4; ++mf)
#pragma unroll
        for (int nf = 0; nf < 2; ++nf) {
            int col = ntile * NT + wn + nf * 16 + lrow;
            float bb12 = b1[col] + b2[col];
            float bb4  = b4[col];
            int row0 = mtile * MT + wm + mf * 16 + lq * 4;
#pragma unroll
            for (int i = 0; i < 4; ++i) {
                float v = accL[mf][nf][i] + bb12
                        + (accP[mf][nf][i] + bb4) * (accQ[mf][nf][i] + bb4);
                obase[(size_t)(row0 + i) * H_DIM + col] = tanhf(v);
            }
        }
}

extern "C" void kernel_launch(void* const* d_in, const int* in_sizes, int n_in,
                              void* d_out, int out_size, void* d_ws, size_t ws_size,
                              hipStream_t stream) {
    (void)in_sizes; (void)n_in; (void)out_size; (void)ws_size;
    const float* x    = (const float*)d_in[0];
    const int*   idxP = (const int*)d_in[1];
    const int*   idxH = (const int*)d_in[2];
    const float* Wp1 = (const float*)d_in[3];  const float* bp1 = (const float*)d_in[4];
    const float* Wp2 = (const float*)d_in[5];  const float* bp2 = (const float*)d_in[6];
    const float* Wp3 = (const float*)d_in[7];
    const float* Wp4 = (const float*)d_in[9];  const float* bp4 = (const float*)d_in[10];
    const float* Wh1 = (const float*)d_in[11]; const float* bh1 = (const float*)d_in[12];
    const float* Wh2 = (const float*)d_in[13]; const float* bh2 = (const float*)d_in[14];
    const float* Wh3 = (const float*)d_in[15];
    const float* Wh4 = (const float*)d_in[17]; const float* bh4 = (const float*)d_in[18];
    float* out = (float*)d_out;
    f16*   ws  = (f16*)d_ws;   // weights 12 MB + x_f16 32 MB = 44 MB

    prep_weights<<<dim3(1024, 2), 256, 0, stream>>>(Wp1, Wp2, Wp3, Wp4,
                                                    Wh1, Wh2, Wh3, Wh4, ws);
    prep_x<<<16384, 256, 0, stream>>>(x, ws + XOFF);
    span_gemm<<<dim3(32, 16, 2), 256, 0, stream>>>(ws + XOFF, idxP, idxH, ws,
                                                   bp1, bp2, bp4, bh1, bh2, bh4, out);
}